// Round 1
// baseline (3139.163 us; speedup 1.0000x reference)
//
#include <hip/hip_runtime.h>
#include <hip/hip_bf16.h>
#include <math.h>

// Problem constants (from reference)
#define BB 64
#define TT 2048
#define VV 4096
#define EE 128
#define H2 128
#define SS 8
#define CC 2
#define NG 1024   // 2 dirs * 4*H2 gate columns in combined EG table

__device__ __forceinline__ float sigf(float x) { return 1.f / (1.f + __expf(-x)); }
__device__ __forceinline__ float tanh_fast(float x) { return 1.f - 2.f / (__expf(2.f * x) + 1.f); }

// ---------------------------------------------------------------------------
// Kernel 1: EG[v, n] = sum_k emb[v,k] * W_comb[n,k] + b_comb[n]
// W_comb rows 0..511 = W_ih_f, rows 512..1023 = W_ih_b. Plain fp32 tiled GEMM
// (exact same math as reference; only 1 GFLOP). Tile 64x64, 256 threads,
// thread computes 4x4, K staged in 2 chunks of 64 (transposed in LDS).
// ---------------------------------------------------------------------------
__global__ __launch_bounds__(256) void eg_gemm(
    const float* __restrict__ emb,
    const float* __restrict__ Wf, const float* __restrict__ bf,
    const float* __restrict__ Wb, const float* __restrict__ bb,
    float* __restrict__ EG)
{
    __shared__ float As[64][68];   // [k_local][m_local], pad 68 for store conflicts + 16B align
    __shared__ float Bs[64][68];   // [k_local][n_local]

    const int tid = threadIdx.x;
    const int tx = tid & 15, ty = tid >> 4;
    const int m0 = blockIdx.y * 64;
    const int n0 = blockIdx.x * 64;

    const float* Bsrc;
    const float* bias;
    if (n0 < 512) { Bsrc = Wf + n0 * EE; bias = bf + n0; }
    else          { Bsrc = Wb + (n0 - 512) * EE; bias = bb + (n0 - 512); }

    float acc[4][4] = {};

    for (int kc = 0; kc < 2; ++kc) {
        // stage 64x64 of A and B, transposed into LDS
        for (int c = tid; c < 1024; c += 256) {
            int r = c >> 4, q = c & 15;
            float4 av = *(const float4*)(emb + (size_t)(m0 + r) * EE + kc * 64 + q * 4);
            As[q * 4 + 0][r] = av.x; As[q * 4 + 1][r] = av.y;
            As[q * 4 + 2][r] = av.z; As[q * 4 + 3][r] = av.w;
            float4 bv = *(const float4*)(Bsrc + (size_t)r * EE + kc * 64 + q * 4);
            Bs[q * 4 + 0][r] = bv.x; Bs[q * 4 + 1][r] = bv.y;
            Bs[q * 4 + 2][r] = bv.z; Bs[q * 4 + 3][r] = bv.w;
        }
        __syncthreads();
        #pragma unroll 8
        for (int k = 0; k < 64; ++k) {
            float4 a4 = *(const float4*)&As[k][4 * ty];
            float4 b4 = *(const float4*)&Bs[k][4 * tx];
            float a[4] = {a4.x, a4.y, a4.z, a4.w};
            float b[4] = {b4.x, b4.y, b4.z, b4.w};
            #pragma unroll
            for (int i = 0; i < 4; ++i)
                #pragma unroll
                for (int jn = 0; jn < 4; ++jn)
                    acc[i][jn] = fmaf(a[i], b[jn], acc[i][jn]);
        }
        __syncthreads();
    }

    #pragma unroll
    for (int i = 0; i < 4; ++i) {
        int m = m0 + 4 * ty + i;
        #pragma unroll
        for (int jn = 0; jn < 4; ++jn) {
            int nn = 4 * tx + jn;
            EG[(size_t)m * NG + n0 + nn] = acc[i][jn] + bias[nn];
        }
    }
}

// ---------------------------------------------------------------------------
// Kernel 2: fused LSTM recurrence + ragged segment max-pool.
// grid = 128 blocks: block (b, dir). 512 threads: thread j owns gate row j
// (PyTorch order i,f,g,o) with W_hh row in 128 VGPRs. h broadcast via LDS.
// Pooling: running max register, flushed at (uniform) segment boundaries.
// ---------------------------------------------------------------------------
__global__ __launch_bounds__(512) void lstm_rec(
    const int* __restrict__ sentence, const int* __restrict__ lens,
    const float* __restrict__ Whhf, const float* __restrict__ Whhb,
    const float* __restrict__ EG, float* __restrict__ pws)
{
    const int bid = blockIdx.x;
    const int b = bid >> 1;
    const int dir = bid & 1;            // 0 = forward, 1 = backward
    const int j = threadIdx.x;          // 0..511 gate index
    const int jj = j & 127;             // hidden unit index (replicated)
    const int L = lens[b];
    const int* srow = sentence + (size_t)b * TT;

    // --- W_hh row j into registers (128 VGPRs) ---
    const float* Wrow = (dir == 0 ? Whhf : Whhb) + (size_t)j * H2;
    float w[128];
    #pragma unroll
    for (int k4 = 0; k4 < 32; ++k4) {
        float4 v = *(const float4*)(Wrow + 4 * k4);
        w[4 * k4 + 0] = v.x; w[4 * k4 + 1] = v.y;
        w[4 * k4 + 2] = v.z; w[4 * k4 + 3] = v.w;
    }

    __shared__ __align__(16) float h_lds[128];
    __shared__ float g_lds[512];
    if (j < 128) h_lds[j] = 0.f;

    const int gofs = dir * 512 + j;     // column in EG
    float c = 0.f;
    float pm = -INFINITY;

    const int wseg = (L + SS - 1) >> 3; // window size
    const bool haspad = (SS * wseg > L);
    const int padlo = L / wseg;         // first padded segment (if haspad)
    int cur_seg = dir ? (SS - 1) : 0;
    int nb = dir ? (SS - 1) * wseg : wseg;  // next boundary

    // --- prefetch pipeline: token & EG row one step ahead ---
    int tt0 = dir ? (L - 1) : 0;
    int tok0 = srow[tt0];
    int t1 = dir ? (L - 2) : 1;
    t1 = max(0, min(TT - 1, t1));
    int tok_next = srow[t1];

    __syncthreads();                    // h_lds init visible

    float xv_cur = EG[(size_t)tok0 * NG + gofs];

    for (int t = 0; t < L; ++t) {
        const int tt = dir ? (L - 1 - t) : t;

        // prefetch EG for t+1 and token for t+2 (values unused past end, indices clamped)
        float xv_next = EG[(size_t)tok_next * NG + gofs];
        int t2 = dir ? (L - 3 - t) : (t + 2);
        t2 = max(0, min(TT - 1, t2));
        int tok_nn = srow[t2];

        // --- gate preactivation: dot(w, h) + xg ---
        float s0 = 0.f, s1 = 0.f, s2 = 0.f, s3 = 0.f;
        const float4* h4 = (const float4*)h_lds;
        #pragma unroll
        for (int k4 = 0; k4 < 32; ++k4) {
            float4 hv = h4[k4];
            s0 = fmaf(w[4 * k4 + 0], hv.x, s0);
            s1 = fmaf(w[4 * k4 + 1], hv.y, s1);
            s2 = fmaf(w[4 * k4 + 2], hv.z, s2);
            s3 = fmaf(w[4 * k4 + 3], hv.w, s3);
        }
        g_lds[j] = xv_cur + ((s0 + s1) + (s2 + s3));
        __syncthreads();

        // --- gate update (replicated across all waves to shorten this phase) ---
        float gi = g_lds[jj];
        float gf = g_lds[128 + jj];
        float gg = g_lds[256 + jj];
        float go2 = g_lds[384 + jj];
        c = sigf(gf) * c + sigf(gi) * tanh_fast(gg);
        float hn = sigf(go2) * tanh_fast(c);

        // --- pooling bookkeeping (uniform branch) ---
        bool bnd = dir ? (tt < nb) : (tt >= nb);
        if (bnd) {
            if (j < 128) {
                float v = pm;
                if (haspad && cur_seg >= padlo) v = fmaxf(v, 0.f);
                pws[(((size_t)b * 2 + dir) * SS + cur_seg) * H2 + j] = v;
            }
            pm = -INFINITY;
            cur_seg += dir ? -1 : 1;
            nb += dir ? -wseg : wseg;
        }
        pm = fmaxf(pm, hn);

        if (j < 128) h_lds[jj] = hn;
        __syncthreads();

        xv_cur = xv_next;
        tok_next = tok_nn;
    }

    if (j < 128) {
        float v = pm;
        if (haspad && cur_seg >= padlo) v = fmaxf(v, 0.f);
        pws[(((size_t)b * 2 + dir) * SS + cur_seg) * H2 + j] = v;
    }
}

// ---------------------------------------------------------------------------
// Kernel 3: out[b,c] = b_dense[c] + sum_k flat[b,k] * W_dense[c,k]
// flat[b, h*S + s] = pooled[b, s, h]; h<128 -> fwd unit h, h>=128 -> bwd h-128.
// pws layout: [b][dir][s][j].
// ---------------------------------------------------------------------------
__global__ __launch_bounds__(256) void dense_k(
    const float* __restrict__ pws, const float* __restrict__ Wd,
    const float* __restrict__ bd, float* __restrict__ out)
{
    const int b = blockIdx.x;
    const int tid = threadIdx.x;
    float a0 = 0.f, a1 = 0.f;
    for (int k = tid; k < 2048; k += 256) {
        int h = k >> 3, s = k & 7;
        int dir = h >> 7, j = h & 127;
        float v = pws[(((size_t)b * 2 + dir) * SS + s) * H2 + j];
        a0 = fmaf(v, Wd[k], a0);
        a1 = fmaf(v, Wd[2048 + k], a1);
    }
    __shared__ float r0[256], r1[256];
    r0[tid] = a0; r1[tid] = a1;
    __syncthreads();
    for (int s = 128; s > 0; s >>= 1) {
        if (tid < s) { r0[tid] += r0[tid + s]; r1[tid] += r1[tid + s]; }
        __syncthreads();
    }
    if (tid == 0) {
        out[b * 2 + 0] = r0[0] + bd[0];
        out[b * 2 + 1] = r1[0] + bd[1];
    }
}

// ---------------------------------------------------------------------------
extern "C" void kernel_launch(void* const* d_in, const int* in_sizes, int n_in,
                              void* d_out, int out_size, void* d_ws, size_t ws_size,
                              hipStream_t stream)
{
    const int*   sentence = (const int*)d_in[0];
    const int*   lens     = (const int*)d_in[1];
    const float* emb      = (const float*)d_in[2];
    const float* Wihf     = (const float*)d_in[3];
    const float* Whhf     = (const float*)d_in[4];
    const float* bf       = (const float*)d_in[5];
    const float* Wihb     = (const float*)d_in[6];
    const float* Whhb     = (const float*)d_in[7];
    const float* bb       = (const float*)d_in[8];
    const float* Wd       = (const float*)d_in[9];
    const float* bd       = (const float*)d_in[10];
    float* out = (float*)d_out;

    float* EG  = (float*)d_ws;                    // [4096][1024] fp32 = 16 MB
    float* pws = EG + (size_t)VV * NG;            // [64][2][8][128] fp32 = 512 KB

    eg_gemm<<<dim3(16, 64), 256, 0, stream>>>(emb, Wihf, bf, Wihb, bb, EG);
    lstm_rec<<<128, 512, 0, stream>>>(sentence, lens, Whhf, Whhb, EG, pws);
    dense_k<<<64, 256, 0, stream>>>(pws, Wd, bd, out);
}